// Round 2
// baseline (113.159 us; speedup 1.0000x reference)
//
#include <hip/hip_runtime.h>
#include <stdint.h>

#define PNUM 128
#define BATCH 8192
#define WPB 4                      // waves per block, 1 batch per wave
#define GRID1 (BATCH / WPB)        // 2048 blocks of 256 threads

typedef _Float16 h2 __attribute__((ext_vector_type(2)));
typedef _Float16 h4 __attribute__((ext_vector_type(4)));
typedef uint32_t u32;

// f32x2 -> f16x2 (RTZ) packed into one u32
__device__ __forceinline__ u32 cvt2u(float x, float y) {
    return __builtin_bit_cast(u32, __builtin_amdgcn_cvt_pkrtz(x, y));
}

// One packed smooth-L1 term over both coords of a point pair, f32-accumulated.
// R7: written as 5 guaranteed packed instructions (R6 counters showed ~2x the
// ideal VALU-issue time -> compiler was emitting a fatter form). Non-volatile
// asm: scheduler may still interleave/hoist freely; DCE kept alive via acc.
//   d = p - q        v_pk_add_f16 neg_lo/neg_hi on src1
//   a = |d|          v_and_b32 0x7fff7fff
//   m = min(a,1)     v_pk_min_f16
//   t = a - 0.5*m    v_pk_fma_f16 (m, -0.5, a)
//   acc += dot2(m,t) v_dot2_f32_f16
__device__ __forceinline__ void unit(u32 p, u32 q, float& acc, u32 cOne, u32 cNegHalf) {
    u32 d, a, m, t;
    asm("v_pk_add_f16 %0, %1, %2 neg_lo:[0,1] neg_hi:[0,1]" : "=v"(d) : "v"(p), "v"(q));
    asm("v_and_b32 %0, 0x7fff7fff, %1" : "=v"(a) : "v"(d));
    asm("v_pk_min_f16 %0, %1, %2" : "=v"(m) : "v"(a), "v"(cOne));
    asm("v_pk_fma_f16 %0, %1, %2, %3" : "=v"(t) : "v"(m), "v"(cNegHalf), "v"(a));
    asm("v_dot2_f32_f16 %0, %1, %2, %0" : "+v"(acc) : "v"(m), "v"(t));
}

// One WAVE per batch, both preds. Lane k owns shifts {2k,2k+1}.
// gt ring (doubled, f16) + pred rows in per-wave LDS. Per hh: 4 j handled;
// 2x ds_read_b64 lane-sliding gather + 2x b128 wave-uniform broadcast.
// All inner-loop values are u32/uint2/uint4 so "lo/hi" extraction is exact
// 32-bit register selection (no shufflevector copies can materialize).
__global__ __launch_bounds__(64 * WPB, 6) void match_fused(
        const float* __restrict__ pred0,
        const float* __restrict__ pred1,
        const float* __restrict__ gt,
        float* __restrict__ out) {
    __shared__ __align__(16) _Float16 lds[WPB][1024];  // ring 512 | p0 256 | p1 256
    __shared__ float bsum[WPB];

    const int t = threadIdx.x;
    const int k = t & 63;
    const int w = __builtin_amdgcn_readfirstlane(t >> 6);
    const int b = blockIdx.x * WPB + w;

    _Float16* base = lds[w];
    uint2* ringU = (uint2*)base;              // 128 entries = 256 points (doubled)
    uint2* q0s   = (uint2*)(base + 512);      // staging view, 64 entries
    uint2* q1s   = (uint2*)(base + 768);

    // ---- stage + f32->f16 convert (own wave's region; no barrier needed) ----
    const float4* gv4 = (const float4*)(gt    + (size_t)b * (PNUM * 2));
    const float4* p0v = (const float4*)(pred0 + (size_t)b * (PNUM * 2));
    const float4* p1v = (const float4*)(pred1 + (size_t)b * (PNUM * 2));
    {
        float4 g = gv4[k];
        uint2 gh = {cvt2u(g.x, g.y), cvt2u(g.z, g.w)};
        ringU[k] = gh; ringU[k + 64] = gh;
        float4 p = p0v[k];
        q0s[k] = (uint2){cvt2u(p.x, p.y), cvt2u(p.z, p.w)};
        p = p1v[k];
        q1s[k] = (uint2){cvt2u(p.x, p.y), cvt2u(p.z, p.w)};
    }

    const uint4* q0U = (const uint4*)(base + 512);  // 32 entries, wave-uniform
    const uint4* q1U = (const uint4*)(base + 768);

    u32 cOne = 0x3C003C00u;      // packed f16 {1.0, 1.0}
    u32 cNegHalf = 0xB800B800u;  // packed f16 {-0.5, -0.5}

    // ---- prologue: iteration 0's operands ----
    uint2 W  = ringU[k];                 // points {2k, 2k+1}
    uint2 na = ringU[k + 1];             // points {2k+2, 2k+3}
    uint2 nb = ringU[k + 2];             // points {2k+4, 2k+5}
    uint4 P0 = q0U[0];
    uint4 P1 = q1U[0];

    float a00 = 0.f, a01 = 0.f, a10 = 0.f, a11 = 0.f;

#pragma unroll 8
    for (int hh = 0; hh < 32; ++hh) {    // j = 4*hh .. 4*hh+3
        // prefetch hh+1 (at hh=31 reads in-bounds LDS garbage, discarded;
        // unmasked index keeps induction linear -> DS offsets stay immediate)
        const int hn = hh + 1;
        uint2 na_n = ringU[k + 2 * hn + 1];
        uint2 nb_n = ringU[k + 2 * hn + 2];
        uint4 P0_n = q0U[hn];
        uint4 P1_n = q1U[hn];

        // pred0: shift 2k, then 2k+1
        unit(P0.x, W.x,  a00, cOne, cNegHalf);
        unit(P0.y, W.y,  a00, cOne, cNegHalf);
        unit(P0.z, na.x, a00, cOne, cNegHalf);
        unit(P0.w, na.y, a00, cOne, cNegHalf);
        unit(P0.x, W.y,  a01, cOne, cNegHalf);
        unit(P0.y, na.x, a01, cOne, cNegHalf);
        unit(P0.z, na.y, a01, cOne, cNegHalf);
        unit(P0.w, nb.x, a01, cOne, cNegHalf);
        // pred1
        unit(P1.x, W.x,  a10, cOne, cNegHalf);
        unit(P1.y, W.y,  a10, cOne, cNegHalf);
        unit(P1.z, na.x, a10, cOne, cNegHalf);
        unit(P1.w, na.y, a10, cOne, cNegHalf);
        unit(P1.x, W.y,  a11, cOne, cNegHalf);
        unit(P1.y, na.x, a11, cOne, cNegHalf);
        unit(P1.z, na.y, a11, cOne, cNegHalf);
        unit(P1.w, nb.x, a11, cOne, cNegHalf);

        // rotate pipeline registers
        W = nb; na = na_n; nb = nb_n; P0 = P0_n; P1 = P1_n;
    }

    // per-pred min over lane's 2 shifts, then over the wave
    float r0 = fminf(a00, a01);
    float r1 = fminf(a10, a11);
#pragma unroll
    for (int m = 32; m > 0; m >>= 1) {
        r0 = fminf(r0, __shfl_xor(r0, m, 64));
        r1 = fminf(r1, __shfl_xor(r1, m, 64));
    }

    if (k == 0) bsum[w] = r0 + r1;
    __syncthreads();
    if (t == 0) {
        float blockpart = bsum[0] + bsum[1] + bsum[2] + bsum[3];
        // relaxed device-scope atomic; NO fence (R5 lesson: fences -> L2 writeback storm)
        atomicAdd(out, blockpart * (1.0f / (2.0f * BATCH * PNUM)));
    }
}

extern "C" void kernel_launch(void* const* d_in, const int* in_sizes, int n_in,
                              void* d_out, int out_size, void* d_ws, size_t ws_size,
                              hipStream_t stream) {
    const float* pred0 = (const float*)d_in[0];
    const float* pred1 = (const float*)d_in[1];
    const float* gt    = (const float*)d_in[2];
    float* out = (float*)d_out;

    (void)hipMemsetAsync(out, 0, sizeof(float), stream);   // out is 0xAA-poisoned
    match_fused<<<GRID1, 64 * WPB, 0, stream>>>(pred0, pred1, gt, out);
}